// Round 4
// baseline (482.340 us; speedup 1.0000x reference)
//
#include <hip/hip_runtime.h>
#include <stdint.h>

#define B_TOK 8192
#define DIM   2048
#define NE    8
#define BM 128
#define BN 128
#define BK 64
#define CVT_BLOCKS 8192   // 1024 float4 per block (4 float4 per thread)
#define GATE_BLOCKS 2048  // 4 tokens per block (1 wave per token)
#define NT3 32            // 2048 / 64 K-tiles for the 256^2 GEMM

typedef __bf16 bf16x8 __attribute__((ext_vector_type(8)));
typedef float  f32x4  __attribute__((ext_vector_type(4)));

__device__ __forceinline__ unsigned short f2b(float f) {
  unsigned u = __builtin_bit_cast(unsigned, f);
  u += 0x7fffu + ((u >> 16) & 1u);   // round-to-nearest-even
  return (unsigned short)(u >> 16);
}
__device__ __forceinline__ uint2 pack4(float4 v) {
  uint2 r;
  r.x = (unsigned)f2b(v.x) | ((unsigned)f2b(v.y) << 16);
  r.y = (unsigned)f2b(v.z) | ((unsigned)f2b(v.w) << 16);
  return r;
}
__device__ __forceinline__ void gload16(const void* g, void* l) {
  __builtin_amdgcn_global_load_lds(
      (const __attribute__((address_space(1))) void*)g,
      (__attribute__((address_space(3))) void*)l, 16, 0, 0);
}

// ---------------- gate (+ optional inpB pack) + We cvt, one launch ---------
// blocks [0, GATE_BLOCKS): gating, exact f64, no atomics, writes eid.
// blocks [GATE_BLOCKS, +CVT_BLOCKS): We f32 -> bf16 (FULL only).
template <bool FULL>
__global__ __launch_bounds__(256) void gate_cvt(
    const float* __restrict__ x,
    const float* __restrict__ y,
    const float* __restrict__ gW,
    const float* __restrict__ gb,
    const float* __restrict__ We,
    int* __restrict__ eid,
    unsigned short* __restrict__ inpB,
    unsigned short* __restrict__ WeB) {
  const int bid = blockIdx.x;
  if (FULL && bid >= GATE_BLOCKS) {
    const int cb = bid - GATE_BLOCKS;
    const size_t base = (size_t)cb * 1024;   // float4 units
#pragma unroll
    for (int j = 0; j < 4; ++j) {
      size_t i4 = base + (size_t)(j * 256 + threadIdx.x);
      float4 v = *(const float4*)(We + i4 * 4);
      *(uint2*)(WeB + i4 * 4) = pack4(v);
    }
    return;
  }

  const int tid = threadIdx.x;
  const int ln = tid & 63;
  const int token = bid * 4 + (tid >> 6);

  double acc[NE];
#pragma unroll
  for (int e = 0; e < NE; ++e) acc[e] = 0.0;

  const float* bases[2] = {x, y};
#pragma unroll
  for (int p = 0; p < 2; ++p) {
    const float* rowp = bases[p] + (size_t)token * 1024;
#pragma unroll
    for (int it = 0; it < 4; ++it) {
      const int d = it * 256 + ln * 4;
      float4 v = *(const float4*)(rowp + d);
      if (FULL)
        *(uint2*)(inpB + (size_t)token * DIM + p * 1024 + d) = pack4(v);
#pragma unroll
      for (int e = 0; e < NE; ++e) {
        float4 g = *(const float4*)(gW + e * DIM + p * 1024 + d);
        acc[e] += (double)v.x * (double)g.x + (double)v.y * (double)g.y +
                  (double)v.z * (double)g.z + (double)v.w * (double)g.w;
      }
    }
  }
#pragma unroll
  for (int e = 0; e < NE; ++e) {
#pragma unroll
    for (int off = 32; off >= 1; off >>= 1) acc[e] += __shfl_xor(acc[e], off, 64);
  }
  if (ln == 0) {
    int best = 0;
    double bv = acc[0] + (double)gb[0];
#pragma unroll
    for (int e = 1; e < NE; ++e) {
      double v = acc[e] + (double)gb[e];
      if (v > bv) { bv = v; best = e; }   // strict > keeps lowest index on ties
    }
    eid[token] = best;
  }
}

// ---------------- bucketize: deterministic ballot-scan (verified r0) -------
__global__ __launch_bounds__(256) void bucket8(const int* __restrict__ eid,
                                               int* __restrict__ counts,
                                               int* __restrict__ perm) {
  const int e = blockIdx.x;
  const int tid = threadIdx.x, ln = tid & 63, wv = tid >> 6;
  __shared__ int wsum[4];
  __shared__ int basev;
  if (tid == 0) basev = 0;
  __syncthreads();
  for (int t0 = 0; t0 < B_TOK; t0 += 256) {
    int t = t0 + tid;
    bool m = (eid[t] == e);
    unsigned long long mk = __ballot(m);
    int pre = __popcll(mk & ((1ull << ln) - 1ull));
    if (ln == 0) wsum[wv] = __popcll(mk);
    __syncthreads();
    int off = basev;
    for (int w = 0; w < wv; ++w) off += wsum[w];
    if (m) perm[e * B_TOK + off + pre] = t;
    __syncthreads();
    if (tid == 0) basev += wsum[0] + wsum[1] + wsum[2] + wsum[3];
    __syncthreads();
  }
  if (tid == 0) counts[e] = basev;
}

// ---------------- 256x256 8-wave pipelined grouped GEMM --------------------
// BK=64, double-buffered LDS (A:[2][256][64], B:[2][256][64] = 128 KiB),
// verified swizzle: slot s of row r holds 16B-chunk s ^ (r&7) (row stride
// 128B -> bank-group = slot, conflict-free; measured 0 conflicts at r0/r2).
// Schedule per K-tile kt (4 quadrant phases (mh,nh)=(0,0),(0,1),(1,1),(1,0)):
//   ph0: STG(kt+1, half0-of-A&B) ; s_waitcnt vmcnt(4) ; barrier ; MFMA q00
//   ph1: STG(kt+1, half1)        ; MFMA q01 ; barrier ...
// vmcnt(4) leaves only the 4 just-issued loads in flight => all 8 loads of
// tile kt (issued during kt-1) landed, uniformly across waves; barrier turns
// per-wave guarantee into all-waves guarantee. Buffers alternate kt&1; the
// write of buf[(kt+1)&1] is ordered after tile kt-1's last read by the
// per-phase barrier chain. Mid-loop never drains vmcnt to 0 (T4).
__global__ __launch_bounds__(512, 2) void moe_gemm3(
    const float* __restrict__ be,
    const unsigned short* __restrict__ inpB,   // bf16 [8192][2048]
    const unsigned short* __restrict__ WeB,    // bf16 [8][2048][2048]
    const int* __restrict__ counts,
    const int* __restrict__ perm,
    float* __restrict__ out) {
  __shared__ __align__(16) unsigned short AB[65536];   // 128 KiB: A@0, B@32768
  __shared__ int tokLds[256];

  const int e = blockIdx.z;
  const int cnt = counts[e];
  const int m0 = blockIdx.y * 256;
  if (m0 >= cnt) return;
  const int n0 = blockIdx.x * 256;

  const int tid = threadIdx.x;
  const int ln = tid & 63;
  const int wv = tid >> 6;     // 0..7
  const int wm = wv & 1;       // M-half of C owned by this wave
  const int wn = wv >> 1;      // 0..3 N-quarter

  if (tid < 256) {
    int r = m0 + tid;
    tokLds[tid] = perm[e * B_TOK + (r < cnt ? r : cnt - 1)];
  }
  __syncthreads();

  // staging: wave wv, issue i covers rows (wv*2+i)*8 + (ln>>3) of a half;
  // lane lands at LDS slot (ln&7) -> fetch global chunk (ln&7)^(ln>>3).
  const int g = (ln & 7) ^ (ln >> 3);
  const unsigned short* wbbase = WeB + (size_t)e * DIM * DIM;
  const unsigned short* aS[2][2];
  const unsigned short* bS[2][2];
#pragma unroll
  for (int h = 0; h < 2; ++h)
#pragma unroll
    for (int i = 0; i < 2; ++i) {
      int row = h * 128 + (wv * 2 + i) * 8 + (ln >> 3);
      aS[h][i] = inpB + (size_t)tokLds[row] * DIM + g * 8;
      bS[h][i] = wbbase + (size_t)(n0 + row) * DIM + g * 8;
    }

  f32x4 acc[8][4];
#pragma unroll
  for (int a = 0; a < 8; ++a)
#pragma unroll
    for (int b = 0; b < 4; ++b) acc[a][b] = (f32x4){0.f, 0.f, 0.f, 0.f};

  auto STG = [&](int kt, int h) {            // one A-half + one B-half
    const int d = (kt & 1) * 16384;
    const int ko = kt * 64;
    gload16(aS[h][0] + ko, &AB[d + h * 8192 + (wv * 2 + 0) * 512]);
    gload16(aS[h][1] + ko, &AB[d + h * 8192 + (wv * 2 + 1) * 512]);
    gload16(bS[h][0] + ko, &AB[32768 + d + h * 8192 + (wv * 2 + 0) * 512]);
    gload16(bS[h][1] + ko, &AB[32768 + d + h * 8192 + (wv * 2 + 1) * 512]);
  };

  auto PHASE = [&](int kt, int mh, int nh) {  // 12 ds_read_b128 + 16 MFMA
    const int d = (kt & 1) * 16384;
    bf16x8 av[4][2], bv[2][2];
#pragma unroll
    for (int f = 0; f < 4; ++f)
#pragma unroll
      for (int ks = 0; ks < 2; ++ks) {
        int r = wm * 128 + mh * 64 + f * 16 + (ln & 15);
        int c = ks * 4 + (ln >> 4);
        av[f][ks] = *(const bf16x8*)&AB[d + r * 64 + ((c ^ (ln & 7))) * 8];
      }
#pragma unroll
    for (int j = 0; j < 2; ++j)
#pragma unroll
      for (int ks = 0; ks < 2; ++ks) {
        int r = wn * 64 + nh * 32 + j * 16 + (ln & 15);
        int c = ks * 4 + (ln >> 4);
        bv[j][ks] = *(const bf16x8*)&AB[32768 + d + r * 64 + ((c ^ (ln & 7))) * 8];
      }
    __builtin_amdgcn_s_setprio(1);
#pragma unroll
    for (int f = 0; f < 4; ++f)
#pragma unroll
      for (int j = 0; j < 2; ++j)
#pragma unroll
        for (int ks = 0; ks < 2; ++ks)
          acc[mh * 4 + f][nh * 2 + j] = __builtin_amdgcn_mfma_f32_16x16x32_bf16(
              av[f][ks], bv[j][ks], acc[mh * 4 + f][nh * 2 + j], 0, 0, 0);
    __builtin_amdgcn_s_setprio(0);
  };

  // prologue: both halves of tile 0 (8 gloads/thread in flight)
  STG(0, 0); STG(0, 1);

  for (int kt = 0; kt < NT3; ++kt) {
    if (kt + 1 < NT3) {
      STG(kt + 1, 0);                                  // 12 in flight
      asm volatile("s_waitcnt vmcnt(4)" ::: "memory"); // tile kt fully landed
    } else {
      asm volatile("s_waitcnt vmcnt(0)" ::: "memory"); // last tile: drain
    }
    __builtin_amdgcn_s_barrier();
    PHASE(kt, 0, 0);
    __builtin_amdgcn_s_barrier();
    if (kt + 1 < NT3) STG(kt + 1, 1);
    PHASE(kt, 0, 1);
    __builtin_amdgcn_s_barrier();
    PHASE(kt, 1, 1);
    __builtin_amdgcn_s_barrier();
    PHASE(kt, 1, 0);
    __builtin_amdgcn_s_barrier();
  }

  // epilogue: += bias, scatter rows by token id, f32 store
  float bias[4]; int col[4];
#pragma unroll
  for (int b = 0; b < 4; ++b) {
    col[b] = n0 + wn * 64 + b * 16 + (ln & 15);
    bias[b] = be[e * DIM + col[b]];
  }
#pragma unroll
  for (int a = 0; a < 8; ++a) {
    int rbase = wm * 128 + a * 16 + ((ln >> 4) << 2);
#pragma unroll
    for (int r = 0; r < 4; ++r) {
      int rl = rbase + r;
      if (m0 + rl < cnt) {
        size_t t = (size_t)tokLds[rl];
#pragma unroll
        for (int b = 0; b < 4; ++b)
          out[t * DIM + col[b]] = acc[a][b][r] + bias[b];
      }
    }
  }
}

// ---------------- fallback GEMM (f32 sources, no workspace) ----------------
__global__ __launch_bounds__(256) void moe_gemm_f32(
    const float* __restrict__ x,
    const float* __restrict__ y,
    const float* __restrict__ We,
    const float* __restrict__ be,
    const int* __restrict__ counts,
    const int* __restrict__ perm,
    float* __restrict__ out) {
  __shared__ unsigned short As[BM * BK];
  __shared__ unsigned short Bs[BN * BK];
  __shared__ int tokLds[BM];

  const int e = blockIdx.z;
  const int cnt = counts[e];
  const int m0 = blockIdx.y * BM;
  if (m0 >= cnt) return;
  const int n0 = blockIdx.x * BN;

  const int tid = threadIdx.x;
  const int ln = tid & 63;
  const int wv = tid >> 6;
  const int wm = wv & 1, wn = wv >> 1;

  if (tid < BM) {
    int r = m0 + tid;
    tokLds[tid] = perm[e * B_TOK + (r < cnt ? r : cnt - 1)];
  }
  __syncthreads();

  const float* wfbase = We + (size_t)e * DIM * DIM;

  f32x4 acc[4][4];
#pragma unroll
  for (int i = 0; i < 4; ++i)
#pragma unroll
    for (int j = 0; j < 4; ++j) acc[i][j] = (f32x4){0.f, 0.f, 0.f, 0.f};

  for (int k0 = 0; k0 < DIM; k0 += BK) {
    __syncthreads();
    const float* ab = (k0 < 1024) ? x : y;
    const int kk = k0 & 1023;
#pragma unroll
    for (int i = 0; i < 8; ++i) {
      int li = i * 256 + tid;
      int row = li >> 4, k4 = li & 15;
      int chunk = k4 >> 1, half = k4 & 1;
      int slot = (chunk ^ (row & 7)) * 2 + half;
      int tok = tokLds[row];
      float4 va = *(const float4*)(ab + (size_t)tok * 1024 + kk + k4 * 4);
      *(uint2*)&As[row * BK + slot * 4] = pack4(va);
      float4 vb = *(const float4*)(wfbase + (size_t)(n0 + row) * DIM + k0 + k4 * 4);
      *(uint2*)&Bs[row * BK + slot * 4] = pack4(vb);
    }
    __syncthreads();

#pragma unroll
    for (int ks = 0; ks < 2; ++ks) {
      bf16x8 av[4], bv[4];
#pragma unroll
      for (int i = 0; i < 4; ++i) {
        int rA = wm * 64 + i * 16 + (ln & 15);
        int c = ks * 4 + (ln >> 4);
        av[i] = *(const bf16x8*)&As[rA * BK + (c ^ (rA & 7)) * 8];
      }
#pragma unroll
      for (int j = 0; j < 4; ++j) {
        int rB = wn * 64 + j * 16 + (ln & 15);
        int c = ks * 4 + (ln >> 4);
        bv[j] = *(const bf16x8*)&Bs[rB * BK + (c ^ (rB & 7)) * 8];
      }
#pragma unroll
      for (int i = 0; i < 4; ++i)
#pragma unroll
        for (int j = 0; j < 4; ++j)
          acc[i][j] = __builtin_amdgcn_mfma_f32_16x16x32_bf16(av[i], bv[j], acc[i][j], 0, 0, 0);
    }
  }

  float bias[4]; int col[4];
#pragma unroll
  for (int j = 0; j < 4; ++j) {
    col[j] = n0 + wn * 64 + j * 16 + (ln & 15);
    bias[j] = be[e * DIM + col[j]];
  }
#pragma unroll
  for (int i = 0; i < 4; ++i) {
    int rbase = wm * 64 + i * 16 + ((ln >> 4) << 2);
#pragma unroll
    for (int r = 0; r < 4; ++r) {
      int rl = rbase + r;
      if (m0 + rl < cnt) {
        size_t t = (size_t)tokLds[rl];
#pragma unroll
        for (int j = 0; j < 4; ++j)
          out[t * DIM + col[j]] = acc[i][j][r] + bias[j];
      }
    }
  }
}

extern "C" void kernel_launch(void* const* d_in, const int* in_sizes, int n_in,
                              void* d_out, int out_size, void* d_ws, size_t ws_size,
                              hipStream_t stream) {
  const float* x  = (const float*)d_in[0];
  const float* y  = (const float*)d_in[1];
  const float* We = (const float*)d_in[2];
  const float* be = (const float*)d_in[3];
  const float* gW = (const float*)d_in[4];
  const float* gb = (const float*)d_in[5];
  float* out = (float*)d_out;

  char* ws = (char*)d_ws;
  int* counts = (int*)ws;                                   // @0, 8 ints (256B pad)
  int* eid    = (int*)(ws + 256);                           // 8192 ints
  int* perm   = (int*)(ws + 33024);                         // 8*8192 ints
  unsigned short* inpB = (unsigned short*)(ws + 295168);    // 33.5 MB bf16 [8192][2048]
  unsigned short* WeB  = (unsigned short*)(ws + 33849600);  // 67.1 MB bf16 [8][2048][2048]
  const size_t needed = 33849600ull + 67108864ull;

  if (ws_size >= needed) {
    gate_cvt<true><<<dim3(GATE_BLOCKS + CVT_BLOCKS), 256, 0, stream>>>(
        x, y, gW, gb, We, eid, inpB, WeB);
    bucket8<<<dim3(NE), 256, 0, stream>>>(eid, counts, perm);
    moe_gemm3<<<dim3(DIM / 256, B_TOK / 256, NE), 512, 0, stream>>>(
        be, inpB, WeB, counts, perm, out);
  } else {
    gate_cvt<false><<<dim3(GATE_BLOCKS), 256, 0, stream>>>(
        x, y, gW, gb, nullptr, eid, nullptr, nullptr);
    bucket8<<<dim3(NE), 256, 0, stream>>>(eid, counts, perm);
    moe_gemm_f32<<<dim3(DIM / BN, B_TOK / BM, NE), 256, 0, stream>>>(
        x, y, We, be, counts, perm, out);
  }
}

// Round 5
// 429.386 us; speedup vs baseline: 1.1233x; 1.1233x over previous
//
#include <hip/hip_runtime.h>
#include <stdint.h>

#define B_TOK 8192
#define DIM   2048
#define NE    8
#define BM 128
#define BN 128
#define BK 64
#define CVT_BLOCKS 8192   // 1024 float4 per block (4 float4 per thread)
#define NT3 32            // 2048 / 64 K-tiles for the 256^2 GEMM

typedef __bf16 bf16x8 __attribute__((ext_vector_type(8)));
typedef float  f32x4  __attribute__((ext_vector_type(4)));

__device__ __forceinline__ unsigned short f2b(float f) {
  unsigned u = __builtin_bit_cast(unsigned, f);
  u += 0x7fffu + ((u >> 16) & 1u);   // round-to-nearest-even
  return (unsigned short)(u >> 16);
}
__device__ __forceinline__ uint2 pack4(float4 v) {
  uint2 r;
  r.x = (unsigned)f2b(v.x) | ((unsigned)f2b(v.y) << 16);
  r.y = (unsigned)f2b(v.z) | ((unsigned)f2b(v.w) << 16);
  return r;
}
__device__ __forceinline__ void gload16(const void* g, void* l) {
  __builtin_amdgcn_global_load_lds(
      (const __attribute__((address_space(1))) void*)g,
      (__attribute__((address_space(3))) void*)l, 16, 0, 0);
}

#define SCHEDB __builtin_amdgcn_sched_barrier(0)
#define BARRIER do { SCHEDB; __builtin_amdgcn_s_barrier(); SCHEDB; } while (0)

// ---------------- gating: one wave per token, exact f64, NO atomics --------
template <bool WINP>
__global__ __launch_bounds__(256) void gate_kernel(
    const float* __restrict__ x,
    const float* __restrict__ y,
    const float* __restrict__ gW,
    const float* __restrict__ gb,
    int* __restrict__ eid,
    unsigned short* __restrict__ inpB) {
  const int tid = threadIdx.x;
  const int ln = tid & 63;
  const int token = blockIdx.x * 4 + (tid >> 6);

  double acc[NE];
#pragma unroll
  for (int e = 0; e < NE; ++e) acc[e] = 0.0;

  const float* bases[2] = {x, y};
#pragma unroll
  for (int p = 0; p < 2; ++p) {
    const float* rowp = bases[p] + (size_t)token * 1024;
#pragma unroll
    for (int it = 0; it < 4; ++it) {
      const int d = it * 256 + ln * 4;
      float4 v = *(const float4*)(rowp + d);
      if (WINP)
        *(uint2*)(inpB + (size_t)token * DIM + p * 1024 + d) = pack4(v);
#pragma unroll
      for (int e = 0; e < NE; ++e) {
        float4 g = *(const float4*)(gW + e * DIM + p * 1024 + d);
        acc[e] += (double)v.x * (double)g.x + (double)v.y * (double)g.y +
                  (double)v.z * (double)g.z + (double)v.w * (double)g.w;
      }
    }
  }
#pragma unroll
  for (int e = 0; e < NE; ++e) {
#pragma unroll
    for (int off = 32; off >= 1; off >>= 1) acc[e] += __shfl_xor(acc[e], off, 64);
  }
  if (ln == 0) {
    int best = 0;
    double bv = acc[0] + (double)gb[0];
#pragma unroll
    for (int e = 1; e < NE; ++e) {
      double v = acc[e] + (double)gb[e];
      if (v > bv) { bv = v; best = e; }   // strict > keeps lowest index on ties
    }
    eid[token] = best;
  }
}

// ---------------- bucketize + We conversion, one launch --------------------
template <bool CVT>
__global__ __launch_bounds__(256) void bucket_cvt(
    const int* __restrict__ eid,
    int* __restrict__ counts,
    int* __restrict__ perm,
    const float* __restrict__ We,
    unsigned short* __restrict__ WeB) {
  if (CVT && blockIdx.x >= NE) {
    const int cb = blockIdx.x - NE;
    const size_t base = (size_t)cb * 1024;   // float4 units
#pragma unroll
    for (int j = 0; j < 4; ++j) {
      size_t i4 = base + (size_t)(j * 256 + threadIdx.x);
      float4 v = *(const float4*)(We + i4 * 4);
      *(uint2*)(WeB + i4 * 4) = pack4(v);
    }
    return;
  }

  const int e = blockIdx.x;
  const int tid = threadIdx.x, ln = tid & 63, wv = tid >> 6;
  __shared__ int wsum[4];
  __shared__ int basev;
  if (tid == 0) basev = 0;
  __syncthreads();
  for (int t0 = 0; t0 < B_TOK; t0 += 256) {
    int t = t0 + tid;
    bool m = (eid[t] == e);
    unsigned long long mk = __ballot(m);
    int pre = __popcll(mk & ((1ull << ln) - 1ull));
    if (ln == 0) wsum[wv] = __popcll(mk);
    __syncthreads();
    int off = basev;
    for (int w = 0; w < wv; ++w) off += wsum[w];
    if (m) perm[e * B_TOK + off + pre] = t;
    __syncthreads();
    if (tid == 0) basev += wsum[0] + wsum[1] + wsum[2] + wsum[3];
    __syncthreads();
  }
  if (tid == 0) counts[e] = basev;
}

// ---------------- 256x256 8-wave grouped GEMM, derived-waits pipeline ------
// Schedule (per K-tile t, buffer d = t&1; quadrant phases q0..q3):
//   q0: read av[mq0](12.. 8) + bv0(4); stage (t+1)A-h0 -> buf (t+1)&1
//   q1: read bv1(4);                   stage (t+1)A-h1
//   q2: read av[mq1](8);               stage (t+2)B-h0 -> buf t&1 (freed: B
//                                      last read q1, drained pre-q1-MFMA)
//   q3: (no reads)                     stage (t+2)B-h1; vmcnt(4)
// Each phase: [reads][stage][q3: vmcnt][barrier][16 MFMA][barrier].
// Register retention: av per m-half (q0->q1, q2->q3), bv0 (q0->q3), bv1
// (q1->q2) => 24 ds_read_b128 / wave / K-tile (vs 48 in the r4 port).
// vmcnt(4) at q3 leaves only {(t+2)B1,(t+2)B0} in flight => (t+1)A1 and all
// older stages landed before [t+1:q0]'s reads ISSUE (one barrier later), so
// every read observes staged data; uniform per-wave waits + barrier make the
// guarantee collective. Mid-loop never drains vmcnt to 0 (T4). WAR hazards:
// stage of a region issues >=1 full barrier after its last readers' lgkm
// drain (reads complete before their own MFMA, which precedes the post-MFMA
// barrier that the staging wave must also cross).
__global__ __launch_bounds__(512, 2) void moe_gemm4(
    const float* __restrict__ be,
    const unsigned short* __restrict__ inpB,   // bf16 [8192][2048]
    const unsigned short* __restrict__ WeB,    // bf16 [8][2048][2048]
    const int* __restrict__ counts,
    const int* __restrict__ perm,
    float* __restrict__ out) {
  __shared__ __align__(16) unsigned short AB[65536];   // A:[2][256][64]@0, B@32768
  __shared__ int tokLds[256];

  const int e = blockIdx.z;
  const int cnt = counts[e];
  const int m0 = blockIdx.y * 256;
  if (m0 >= cnt) return;
  const int n0 = blockIdx.x * 256;

  const int tid = threadIdx.x;
  const int ln = tid & 63;
  const int wv = tid >> 6;     // 0..7
  const int wm = wv & 1;       // M-half (128 rows) of C owned by this wave
  const int wn = wv >> 1;      // 0..3 N-quarter (64 cols)

  if (tid < 256) {
    int r = m0 + tid;
    tokLds[tid] = perm[e * B_TOK + (r < cnt ? r : cnt - 1)];
  }
  __syncthreads();

  // staging geometry (r4-verified): wave wv, issue i covers 8 rows of a
  // 128-row half; lane -> row += (ln>>3), LDS slot (ln&7); fetch global
  // chunk (ln&7)^(ln>>3) so slot s of row r holds chunk s ^ (r&7).
  const int g = (ln & 7) ^ (ln >> 3);
  const unsigned short* wbbase = WeB + (size_t)e * DIM * DIM;
  const unsigned short* aS[2][2];
  const unsigned short* bS[2][2];
#pragma unroll
  for (int h = 0; h < 2; ++h)
#pragma unroll
    for (int i = 0; i < 2; ++i) {
      int row = h * 128 + (wv * 2 + i) * 8 + (ln >> 3);
      aS[h][i] = inpB + (size_t)tokLds[row] * DIM + g * 8;
      bS[h][i] = wbbase + (size_t)(n0 + row) * DIM + g * 8;
    }

  f32x4 acc[8][4];
#pragma unroll
  for (int a = 0; a < 8; ++a)
#pragma unroll
    for (int b = 0; b < 4; ++b) acc[a][b] = (f32x4){0.f, 0.f, 0.f, 0.f};

  // fragment-read constants (r4-verified): row = base + (ln&15); chunk
  // c = ks*4 + (ln>>4); slot = c ^ (row&7) = c ^ (ln&7).
  const int aBase = (wm * 128 + (ln & 15)) * 64;   // shorts; + mq*4096 + f*1024
  const int bBase = (wn * 64 + (ln & 15)) * 64;    // shorts; + nq*2048 + j*1024
  const int ofk0 = (((ln >> 4)) ^ (ln & 7)) * 8;
  const int ofk1 = ((4 + (ln >> 4)) ^ (ln & 7)) * 8;

  auto SA = [&](int tt, int h) {
    if (tt >= NT3) return;
    const int dd = (tt & 1) * 16384;
    const int ko = tt * 64;
    gload16(aS[h][0] + ko, &AB[dd + h * 8192 + (wv * 2 + 0) * 512]);
    gload16(aS[h][1] + ko, &AB[dd + h * 8192 + (wv * 2 + 1) * 512]);
  };
  auto SBst = [&](int tt, int h) {
    if (tt >= NT3) return;
    const int dd = (tt & 1) * 16384;
    const int ko = tt * 64;
    gload16(bS[h][0] + ko, &AB[32768 + dd + h * 8192 + (wv * 2 + 0) * 512]);
    gload16(bS[h][1] + ko, &AB[32768 + dd + h * 8192 + (wv * 2 + 1) * 512]);
  };
  auto RAV = [&](bf16x8 (&av)[4][2], int d, int mq) {
#pragma unroll
    for (int f = 0; f < 4; ++f) {
      av[f][0] = *(const bf16x8*)&AB[d + aBase + mq * 4096 + f * 1024 + ofk0];
      av[f][1] = *(const bf16x8*)&AB[d + aBase + mq * 4096 + f * 1024 + ofk1];
    }
  };
  auto RBV = [&](bf16x8 (&bv)[2][2], int d, int nq) {
#pragma unroll
    for (int j = 0; j < 2; ++j) {
      bv[j][0] = *(const bf16x8*)&AB[32768 + d + bBase + nq * 2048 + j * 1024 + ofk0];
      bv[j][1] = *(const bf16x8*)&AB[32768 + d + bBase + nq * 2048 + j * 1024 + ofk1];
    }
  };
  auto QM = [&](int mq, int nq, bf16x8 (&av)[4][2], bf16x8 (&bv)[2][2]) {
    __builtin_amdgcn_s_setprio(1);
#pragma unroll
    for (int f = 0; f < 4; ++f)
#pragma unroll
      for (int j = 0; j < 2; ++j)
#pragma unroll
        for (int ks = 0; ks < 2; ++ks)
          acc[mq * 4 + f][nq * 2 + j] = __builtin_amdgcn_mfma_f32_16x16x32_bf16(
              av[f][ks], bv[j][ks], acc[mq * 4 + f][nq * 2 + j], 0, 0, 0);
    __builtin_amdgcn_s_setprio(0);
  };

  // prologue: tile0 all halves + tile1 B halves (12 loads/thread, issue
  // order 0A0,0A1,0B0,0B1,1B0,1B1); vmcnt(4) -> tile0 landed, {1B*} fly.
  SA(0, 0); SA(0, 1); SBst(0, 0); SBst(0, 1); SBst(1, 0); SBst(1, 1);
  asm volatile("s_waitcnt vmcnt(4)" ::: "memory");
  BARRIER;

  for (int t = 0; t < NT3; ++t) {
    const int d = (t & 1) * 16384;
    bf16x8 av[4][2], bv0[2][2], bv1[2][2];
    // ---- q0: C-quadrant (mq0, nq0)
    RAV(av, d, 0); RBV(bv0, d, 0);
    SA(t + 1, 0);
    BARRIER;
    QM(0, 0, av, bv0);
    BARRIER;
    // ---- q1: (mq0, nq1)   [av retained]
    RBV(bv1, d, 1);
    SA(t + 1, 1);
    BARRIER;
    QM(0, 1, av, bv1);
    BARRIER;
    // ---- q2: (mq1, nq1)   [bv1 retained]
    RAV(av, d, 1);
    SBst(t + 2, 0);
    BARRIER;
    QM(1, 1, av, bv1);
    BARRIER;
    // ---- q3: (mq1, nq0)   [av, bv0 retained; no reads]
    SBst(t + 2, 1);
    if (t < NT3 - 2) {
      asm volatile("s_waitcnt vmcnt(4)" ::: "memory");  // next tile landed
    } else {
      asm volatile("s_waitcnt vmcnt(0)" ::: "memory");  // tail drain
    }
    BARRIER;
    QM(1, 0, av, bv0);
    BARRIER;
  }

  // epilogue: += bias, scatter rows by token id, f32 store (r4-verified)
  float bias[4]; int col[4];
#pragma unroll
  for (int b = 0; b < 4; ++b) {
    col[b] = n0 + wn * 64 + b * 16 + (ln & 15);
    bias[b] = be[e * DIM + col[b]];
  }
#pragma unroll
  for (int a = 0; a < 8; ++a) {
    int rbase = wm * 128 + a * 16 + ((ln >> 4) << 2);
#pragma unroll
    for (int r = 0; r < 4; ++r) {
      int rl = rbase + r;
      if (m0 + rl < cnt) {
        size_t t = (size_t)tokLds[rl];
#pragma unroll
        for (int b = 0; b < 4; ++b)
          out[t * DIM + col[b]] = acc[a][b][r] + bias[b];
      }
    }
  }
}

// ---------------- fallback GEMM (f32 sources, no workspace) ----------------
__global__ __launch_bounds__(256) void moe_gemm_f32(
    const float* __restrict__ x,
    const float* __restrict__ y,
    const float* __restrict__ We,
    const float* __restrict__ be,
    const int* __restrict__ counts,
    const int* __restrict__ perm,
    float* __restrict__ out) {
  __shared__ unsigned short As[BM * BK];
  __shared__ unsigned short Bs[BN * BK];
  __shared__ int tokLds[BM];

  const int e = blockIdx.z;
  const int cnt = counts[e];
  const int m0 = blockIdx.y * BM;
  if (m0 >= cnt) return;
  const int n0 = blockIdx.x * BN;

  const int tid = threadIdx.x;
  const int ln = tid & 63;
  const int wv = tid >> 6;
  const int wm = wv & 1, wn = wv >> 1;

  if (tid < BM) {
    int r = m0 + tid;
    tokLds[tid] = perm[e * B_TOK + (r < cnt ? r : cnt - 1)];
  }
  __syncthreads();

  const float* wfbase = We + (size_t)e * DIM * DIM;

  f32x4 acc[4][4];
#pragma unroll
  for (int i = 0; i < 4; ++i)
#pragma unroll
    for (int j = 0; j < 4; ++j) acc[i][j] = (f32x4){0.f, 0.f, 0.f, 0.f};

  for (int k0 = 0; k0 < DIM; k0 += BK) {
    __syncthreads();
    const float* ab = (k0 < 1024) ? x : y;
    const int kk = k0 & 1023;
#pragma unroll
    for (int i = 0; i < 8; ++i) {
      int li = i * 256 + tid;
      int row = li >> 4, k4 = li & 15;
      int chunk = k4 >> 1, half = k4 & 1;
      int slot = (chunk ^ (row & 7)) * 2 + half;
      int tok = tokLds[row];
      float4 va = *(const float4*)(ab + (size_t)tok * 1024 + kk + k4 * 4);
      *(uint2*)&As[row * BK + slot * 4] = pack4(va);
      float4 vb = *(const float4*)(wfbase + (size_t)(n0 + row) * DIM + k0 + k4 * 4);
      *(uint2*)&Bs[row * BK + slot * 4] = pack4(vb);
    }
    __syncthreads();

#pragma unroll
    for (int ks = 0; ks < 2; ++ks) {
      bf16x8 av[4], bv[4];
#pragma unroll
      for (int i = 0; i < 4; ++i) {
        int rA = wm * 64 + i * 16 + (ln & 15);
        int c = ks * 4 + (ln >> 4);
        av[i] = *(const bf16x8*)&As[rA * BK + (c ^ (rA & 7)) * 8];
      }
#pragma unroll
      for (int j = 0; j < 4; ++j) {
        int rB = wn * 64 + j * 16 + (ln & 15);
        int c = ks * 4 + (ln >> 4);
        bv[j] = *(const bf16x8*)&Bs[rB * BK + (c ^ (rB & 7)) * 8];
      }
#pragma unroll
      for (int i = 0; i < 4; ++i)
#pragma unroll
        for (int j = 0; j < 4; ++j)
          acc[i][j] = __builtin_amdgcn_mfma_f32_16x16x32_bf16(av[i], bv[j], acc[i][j], 0, 0, 0);
    }
  }

  float bias[4]; int col[4];
#pragma unroll
  for (int j = 0; j < 4; ++j) {
    col[j] = n0 + wn * 64 + j * 16 + (ln & 15);
    bias[j] = be[e * DIM + col[j]];
  }
#pragma unroll
  for (int i = 0; i < 4; ++i) {
    int rbase = wm * 64 + i * 16 + ((ln >> 4) << 2);
#pragma unroll
    for (int r = 0; r < 4; ++r) {
      int rl = rbase + r;
      if (m0 + rl < cnt) {
        size_t t = (size_t)tokLds[rl];
#pragma unroll
        for (int j = 0; j < 4; ++j)
          out[t * DIM + col[j]] = acc[i][j][r] + bias[j];
      }
    }
  }
}

extern "C" void kernel_launch(void* const* d_in, const int* in_sizes, int n_in,
                              void* d_out, int out_size, void* d_ws, size_t ws_size,
                              hipStream_t stream) {
  const float* x  = (const float*)d_in[0];
  const float* y  = (const float*)d_in[1];
  const float* We = (const float*)d_in[2];
  const float* be = (const float*)d_in[3];
  const float* gW = (const float*)d_in[4];
  const float* gb = (const float*)d_in[5];
  float* out = (float*)d_out;

  char* ws = (char*)d_ws;
  int* counts = (int*)ws;                                   // @0, 8 ints (256B pad)
  int* eid    = (int*)(ws + 256);                           // 8192 ints
  int* perm   = (int*)(ws + 33024);                         // 8*8192 ints
  unsigned short* inpB = (unsigned short*)(ws + 295168);    // 33.5 MB bf16 [8192][2048]
  unsigned short* WeB  = (unsigned short*)(ws + 33849600);  // 67.1 MB bf16 [8][2048][2048]
  const size_t needed = 33849600ull + 67108864ull;

  if (ws_size >= needed) {
    gate_kernel<true><<<dim3(B_TOK / 4), 256, 0, stream>>>(x, y, gW, gb, eid, inpB);
    bucket_cvt<true><<<dim3(NE + CVT_BLOCKS), 256, 0, stream>>>(eid, counts, perm, We, WeB);
    moe_gemm4<<<dim3(DIM / 256, B_TOK / 256, NE), 512, 0, stream>>>(
        be, inpB, WeB, counts, perm, out);
  } else {
    gate_kernel<false><<<dim3(B_TOK / 4), 256, 0, stream>>>(x, y, gW, gb, eid, nullptr);
    bucket_cvt<false><<<dim3(NE), 256, 0, stream>>>(eid, counts, perm, nullptr, nullptr);
    moe_gemm_f32<<<dim3(DIM / BN, B_TOK / BM, NE), 256, 0, stream>>>(
        x, y, We, be, counts, perm, out);
  }
}

// Round 6
// 399.596 us; speedup vs baseline: 1.2071x; 1.0745x over previous
//
#include <hip/hip_runtime.h>
#include <stdint.h>

#define B_TOK 8192
#define DIM   2048
#define NE    8
#define BM 128
#define BN 128
#define BK 64
#define CVT_BLOCKS 8192   // 1024 float4 per block (4 float4 per thread)
#define NT3 32            // 2048 / 64 K-tiles for the 256^2 GEMM

typedef __bf16 bf16x8 __attribute__((ext_vector_type(8)));
typedef float  f32x4  __attribute__((ext_vector_type(4)));

__device__ __forceinline__ unsigned short f2b(float f) {
  unsigned u = __builtin_bit_cast(unsigned, f);
  u += 0x7fffu + ((u >> 16) & 1u);   // round-to-nearest-even
  return (unsigned short)(u >> 16);
}
__device__ __forceinline__ uint2 pack4(float4 v) {
  uint2 r;
  r.x = (unsigned)f2b(v.x) | ((unsigned)f2b(v.y) << 16);
  r.y = (unsigned)f2b(v.z) | ((unsigned)f2b(v.w) << 16);
  return r;
}
__device__ __forceinline__ uint2 pack4(f32x4 v) {
  uint2 r;
  r.x = (unsigned)f2b(v.x) | ((unsigned)f2b(v.y) << 16);
  r.y = (unsigned)f2b(v.z) | ((unsigned)f2b(v.w) << 16);
  return r;
}
__device__ __forceinline__ void gload16(const void* g, void* l) {
  __builtin_amdgcn_global_load_lds(
      (const __attribute__((address_space(1))) void*)g,
      (__attribute__((address_space(3))) void*)l, 16, 0, 0);
}

#define SCHEDB __builtin_amdgcn_sched_barrier(0)
#define BARRIER do { SCHEDB; __builtin_amdgcn_s_barrier(); SCHEDB; } while (0)

// ---------------- gating: one wave per token, exact f64, NO atomics --------
template <bool WINP>
__global__ __launch_bounds__(256) void gate_kernel(
    const float* __restrict__ x,
    const float* __restrict__ y,
    const float* __restrict__ gW,
    const float* __restrict__ gb,
    int* __restrict__ eid,
    unsigned short* __restrict__ inpB) {
  const int tid = threadIdx.x;
  const int ln = tid & 63;
  const int token = blockIdx.x * 4 + (tid >> 6);

  double acc[NE];
#pragma unroll
  for (int e = 0; e < NE; ++e) acc[e] = 0.0;

  const float* bases[2] = {x, y};
#pragma unroll
  for (int p = 0; p < 2; ++p) {
    const float* rowp = bases[p] + (size_t)token * 1024;
#pragma unroll
    for (int it = 0; it < 4; ++it) {
      const int d = it * 256 + ln * 4;
      float4 v = *(const float4*)(rowp + d);
      if (WINP)
        *(uint2*)(inpB + (size_t)token * DIM + p * 1024 + d) = pack4(v);
#pragma unroll
      for (int e = 0; e < NE; ++e) {
        float4 g = *(const float4*)(gW + e * DIM + p * 1024 + d);
        acc[e] += (double)v.x * (double)g.x + (double)v.y * (double)g.y +
                  (double)v.z * (double)g.z + (double)v.w * (double)g.w;
      }
    }
  }
#pragma unroll
  for (int e = 0; e < NE; ++e) {
#pragma unroll
    for (int off = 32; off >= 1; off >>= 1) acc[e] += __shfl_xor(acc[e], off, 64);
  }
  if (ln == 0) {
    int best = 0;
    double bv = acc[0] + (double)gb[0];
#pragma unroll
    for (int e = 1; e < NE; ++e) {
      double v = acc[e] + (double)gb[e];
      if (v > bv) { bv = v; best = e; }   // strict > keeps lowest index on ties
    }
    eid[token] = best;
  }
}

// ---------------- bucketize + We conversion, one launch --------------------
// We f32 read is NON-TEMPORAL: the 268 MB stream must not evict inpB/WeB
// from L3 (they are the GEMM's inputs, produced immediately before).
template <bool CVT>
__global__ __launch_bounds__(256) void bucket_cvt(
    const int* __restrict__ eid,
    int* __restrict__ counts,
    int* __restrict__ perm,
    const float* __restrict__ We,
    unsigned short* __restrict__ WeB) {
  if (CVT && blockIdx.x >= NE) {
    const int cb = blockIdx.x - NE;
    const size_t base = (size_t)cb * 1024;   // float4 units
#pragma unroll
    for (int j = 0; j < 4; ++j) {
      size_t i4 = base + (size_t)(j * 256 + threadIdx.x);
      f32x4 v = __builtin_nontemporal_load((const f32x4*)We + i4);
      *(uint2*)(WeB + i4 * 4) = pack4(v);
    }
    return;
  }

  const int e = blockIdx.x;
  const int tid = threadIdx.x, ln = tid & 63, wv = tid >> 6;
  __shared__ int wsum[4];
  __shared__ int basev;
  if (tid == 0) basev = 0;
  __syncthreads();
  for (int t0 = 0; t0 < B_TOK; t0 += 256) {
    int t = t0 + tid;
    bool m = (eid[t] == e);
    unsigned long long mk = __ballot(m);
    int pre = __popcll(mk & ((1ull << ln) - 1ull));
    if (ln == 0) wsum[wv] = __popcll(mk);
    __syncthreads();
    int off = basev;
    for (int w = 0; w < wv; ++w) off += wsum[w];
    if (m) perm[e * B_TOK + off + pre] = t;
    __syncthreads();
    if (tid == 0) basev += wsum[0] + wsum[1] + wsum[2] + wsum[3];
    __syncthreads();
  }
  if (tid == 0) counts[e] = basev;
}

// ---------------- 256x256 8-wave grouped GEMM, derived-waits pipeline ------
// Schedule identical to r5 (verified). NEW: 1-D grid with expert->XCD
// mapping: bid&7 == expert, so all ~32 active blocks of an expert land on
// one XCD (dispatch round-robins bid%8 over XCDs). The 4 same-B-panel
// M-blocks and 8 same-A N-blocks then share ONE L2: per-K-tile unique
// working set = 384 KB << 4 MB L2, turning the measured 4x B / 8x A HBM
// re-fetch (FETCH 174 MB) into L2 temporal hits (~100 MB unique).
// out stores are non-temporal (never re-read; don't evict B panels).
__global__ __launch_bounds__(512, 2) void moe_gemm4(
    const float* __restrict__ be,
    const unsigned short* __restrict__ inpB,   // bf16 [8192][2048]
    const unsigned short* __restrict__ WeB,    // bf16 [8][2048][2048]
    const int* __restrict__ counts,
    const int* __restrict__ perm,
    float* __restrict__ out) {
  __shared__ __align__(16) unsigned short AB[65536];   // A:[2][256][64]@0, B@32768
  __shared__ int tokLds[256];

  const int bid = blockIdx.x;
  const int e = bid & 7;            // XCD id == expert id
  const int j = bid >> 3;
  const int n0 = (j & 7) * 256;
  const int m0 = (j >> 3) * 256;
  const int cnt = counts[e];
  if (m0 >= cnt) return;

  const int tid = threadIdx.x;
  const int ln = tid & 63;
  const int wv = tid >> 6;     // 0..7
  const int wm = wv & 1;       // M-half (128 rows) of C owned by this wave
  const int wn = wv >> 1;      // 0..3 N-quarter (64 cols)

  if (tid < 256) {
    int r = m0 + tid;
    tokLds[tid] = perm[e * B_TOK + (r < cnt ? r : cnt - 1)];
  }
  __syncthreads();

  // staging geometry (r4/r5-verified): wave wv, issue i covers 8 rows of a
  // 128-row half; lane -> row += (ln>>3), LDS slot (ln&7); fetch global
  // chunk (ln&7)^(ln>>3) so slot s of row r holds chunk s ^ (r&7).
  const int g = (ln & 7) ^ (ln >> 3);
  const unsigned short* wbbase = WeB + (size_t)e * DIM * DIM;
  const unsigned short* aS[2][2];
  const unsigned short* bS[2][2];
#pragma unroll
  for (int h = 0; h < 2; ++h)
#pragma unroll
    for (int i = 0; i < 2; ++i) {
      int row = h * 128 + (wv * 2 + i) * 8 + (ln >> 3);
      aS[h][i] = inpB + (size_t)tokLds[row] * DIM + g * 8;
      bS[h][i] = wbbase + (size_t)(n0 + row) * DIM + g * 8;
    }

  f32x4 acc[8][4];
#pragma unroll
  for (int a = 0; a < 8; ++a)
#pragma unroll
    for (int b = 0; b < 4; ++b) acc[a][b] = (f32x4){0.f, 0.f, 0.f, 0.f};

  // fragment-read constants (verified): row = base + (ln&15); chunk
  // c = ks*4 + (ln>>4); slot = c ^ (row&7) = c ^ (ln&7).
  const int aBase = (wm * 128 + (ln & 15)) * 64;   // shorts; + mq*4096 + f*1024
  const int bBase = (wn * 64 + (ln & 15)) * 64;    // shorts; + nq*2048 + j*1024
  const int ofk0 = (((ln >> 4)) ^ (ln & 7)) * 8;
  const int ofk1 = ((4 + (ln >> 4)) ^ (ln & 7)) * 8;

  auto SA = [&](int tt, int h) {
    if (tt >= NT3) return;
    const int dd = (tt & 1) * 16384;
    const int ko = tt * 64;
    gload16(aS[h][0] + ko, &AB[dd + h * 8192 + (wv * 2 + 0) * 512]);
    gload16(aS[h][1] + ko, &AB[dd + h * 8192 + (wv * 2 + 1) * 512]);
  };
  auto SBst = [&](int tt, int h) {
    if (tt >= NT3) return;
    const int dd = (tt & 1) * 16384;
    const int ko = tt * 64;
    gload16(bS[h][0] + ko, &AB[32768 + dd + h * 8192 + (wv * 2 + 0) * 512]);
    gload16(bS[h][1] + ko, &AB[32768 + dd + h * 8192 + (wv * 2 + 1) * 512]);
  };
  auto RAV = [&](bf16x8 (&av)[4][2], int d, int mq) {
#pragma unroll
    for (int f = 0; f < 4; ++f) {
      av[f][0] = *(const bf16x8*)&AB[d + aBase + mq * 4096 + f * 1024 + ofk0];
      av[f][1] = *(const bf16x8*)&AB[d + aBase + mq * 4096 + f * 1024 + ofk1];
    }
  };
  auto RBV = [&](bf16x8 (&bv)[2][2], int d, int nq) {
#pragma unroll
    for (int jj = 0; jj < 2; ++jj) {
      bv[jj][0] = *(const bf16x8*)&AB[32768 + d + bBase + nq * 2048 + jj * 1024 + ofk0];
      bv[jj][1] = *(const bf16x8*)&AB[32768 + d + bBase + nq * 2048 + jj * 1024 + ofk1];
    }
  };
  auto QM = [&](int mq, int nq, bf16x8 (&av)[4][2], bf16x8 (&bv)[2][2]) {
    __builtin_amdgcn_s_setprio(1);
#pragma unroll
    for (int f = 0; f < 4; ++f)
#pragma unroll
      for (int jj = 0; jj < 2; ++jj)
#pragma unroll
        for (int ks = 0; ks < 2; ++ks)
          acc[mq * 4 + f][nq * 2 + jj] = __builtin_amdgcn_mfma_f32_16x16x32_bf16(
              av[f][ks], bv[jj][ks], acc[mq * 4 + f][nq * 2 + jj], 0, 0, 0);
    __builtin_amdgcn_s_setprio(0);
  };

  // prologue: tile0 all halves + tile1 B halves (12 loads/thread, issue
  // order 0A0,0A1,0B0,0B1,1B0,1B1); vmcnt(4) -> tile0 landed, {1B*} fly.
  SA(0, 0); SA(0, 1); SBst(0, 0); SBst(0, 1); SBst(1, 0); SBst(1, 1);
  asm volatile("s_waitcnt vmcnt(4)" ::: "memory");
  BARRIER;

  for (int t = 0; t < NT3; ++t) {
    const int d = (t & 1) * 16384;
    bf16x8 av[4][2], bv0[2][2], bv1[2][2];
    // ---- q0: C-quadrant (mq0, nq0)
    RAV(av, d, 0); RBV(bv0, d, 0);
    SA(t + 1, 0);
    BARRIER;
    QM(0, 0, av, bv0);
    BARRIER;
    // ---- q1: (mq0, nq1)   [av retained]
    RBV(bv1, d, 1);
    SA(t + 1, 1);
    BARRIER;
    QM(0, 1, av, bv1);
    BARRIER;
    // ---- q2: (mq1, nq1)   [bv1 retained]
    RAV(av, d, 1);
    SBst(t + 2, 0);
    BARRIER;
    QM(1, 1, av, bv1);
    BARRIER;
    // ---- q3: (mq1, nq0)   [av, bv0 retained; no reads]
    SBst(t + 2, 1);
    if (t < NT3 - 2) {
      asm volatile("s_waitcnt vmcnt(4)" ::: "memory");  // next tile landed
    } else {
      asm volatile("s_waitcnt vmcnt(0)" ::: "memory");  // tail drain
    }
    BARRIER;
    QM(1, 0, av, bv0);
    BARRIER;
  }

  // epilogue: += bias, scatter rows by token id, non-temporal f32 store
  float bias[4]; int col[4];
#pragma unroll
  for (int b = 0; b < 4; ++b) {
    col[b] = n0 + wn * 64 + b * 16 + (ln & 15);
    bias[b] = be[e * DIM + col[b]];
  }
#pragma unroll
  for (int a = 0; a < 8; ++a) {
    int rbase = wm * 128 + a * 16 + ((ln >> 4) << 2);
#pragma unroll
    for (int r = 0; r < 4; ++r) {
      int rl = rbase + r;
      if (m0 + rl < cnt) {
        size_t t = (size_t)tokLds[rl];
#pragma unroll
        for (int b = 0; b < 4; ++b)
          __builtin_nontemporal_store(acc[a][b][r] + bias[b],
                                      &out[t * DIM + col[b]]);
      }
    }
  }
}

// ---------------- fallback GEMM (f32 sources, no workspace) ----------------
__global__ __launch_bounds__(256) void moe_gemm_f32(
    const float* __restrict__ x,
    const float* __restrict__ y,
    const float* __restrict__ We,
    const float* __restrict__ be,
    const int* __restrict__ counts,
    const int* __restrict__ perm,
    float* __restrict__ out) {
  __shared__ unsigned short As[BM * BK];
  __shared__ unsigned short Bs[BN * BK];
  __shared__ int tokLds[BM];

  const int e = blockIdx.z;
  const int cnt = counts[e];
  const int m0 = blockIdx.y * BM;
  if (m0 >= cnt) return;
  const int n0 = blockIdx.x * BN;

  const int tid = threadIdx.x;
  const int ln = tid & 63;
  const int wv = tid >> 6;
  const int wm = wv & 1, wn = wv >> 1;

  if (tid < BM) {
    int r = m0 + tid;
    tokLds[tid] = perm[e * B_TOK + (r < cnt ? r : cnt - 1)];
  }
  __syncthreads();

  const float* wfbase = We + (size_t)e * DIM * DIM;

  f32x4 acc[4][4];
#pragma unroll
  for (int i = 0; i < 4; ++i)
#pragma unroll
    for (int j = 0; j < 4; ++j) acc[i][j] = (f32x4){0.f, 0.f, 0.f, 0.f};

  for (int k0 = 0; k0 < DIM; k0 += BK) {
    __syncthreads();
    const float* ab = (k0 < 1024) ? x : y;
    const int kk = k0 & 1023;
#pragma unroll
    for (int i = 0; i < 8; ++i) {
      int li = i * 256 + tid;
      int row = li >> 4, k4 = li & 15;
      int chunk = k4 >> 1, half = k4 & 1;
      int slot = (chunk ^ (row & 7)) * 2 + half;
      int tok = tokLds[row];
      float4 va = *(const float4*)(ab + (size_t)tok * 1024 + kk + k4 * 4);
      *(uint2*)&As[row * BK + slot * 4] = pack4(va);
      float4 vb = *(const float4*)(wfbase + (size_t)(n0 + row) * DIM + k0 + k4 * 4);
      *(uint2*)&Bs[row * BK + slot * 4] = pack4(vb);
    }
    __syncthreads();

#pragma unroll
    for (int ks = 0; ks < 2; ++ks) {
      bf16x8 av[4], bv[4];
#pragma unroll
      for (int i = 0; i < 4; ++i) {
        int rA = wm * 64 + i * 16 + (ln & 15);
        int c = ks * 4 + (ln >> 4);
        av[i] = *(const bf16x8*)&As[rA * BK + (c ^ (rA & 7)) * 8];
      }
#pragma unroll
      for (int j = 0; j < 4; ++j) {
        int rB = wn * 64 + j * 16 + (ln & 15);
        int c = ks * 4 + (ln >> 4);
        bv[j] = *(const bf16x8*)&Bs[rB * BK + (c ^ (rB & 7)) * 8];
      }
#pragma unroll
      for (int i = 0; i < 4; ++i)
#pragma unroll
        for (int j = 0; j < 4; ++j)
          acc[i][j] = __builtin_amdgcn_mfma_f32_16x16x32_bf16(av[i], bv[j], acc[i][j], 0, 0, 0);
    }
  }

  float bias[4]; int col[4];
#pragma unroll
  for (int j = 0; j < 4; ++j) {
    col[j] = n0 + wn * 64 + j * 16 + (ln & 15);
    bias[j] = be[e * DIM + col[j]];
  }
#pragma unroll
  for (int i = 0; i < 4; ++i) {
    int rbase = wm * 64 + i * 16 + ((ln >> 4) << 2);
#pragma unroll
    for (int r = 0; r < 4; ++r) {
      int rl = rbase + r;
      if (m0 + rl < cnt) {
        size_t t = (size_t)tokLds[rl];
#pragma unroll
        for (int j = 0; j < 4; ++j)
          out[t * DIM + col[j]] = acc[i][j][r] + bias[j];
      }
    }
  }
}

extern "C" void kernel_launch(void* const* d_in, const int* in_sizes, int n_in,
                              void* d_out, int out_size, void* d_ws, size_t ws_size,
                              hipStream_t stream) {
  const float* x  = (const float*)d_in[0];
  const float* y  = (const float*)d_in[1];
  const float* We = (const float*)d_in[2];
  const float* be = (const float*)d_in[3];
  const float* gW = (const float*)d_in[4];
  const float* gb = (const float*)d_in[5];
  float* out = (float*)d_out;

  char* ws = (char*)d_ws;
  int* counts = (int*)ws;                                   // @0, 8 ints (256B pad)
  int* eid    = (int*)(ws + 256);                           // 8192 ints
  int* perm   = (int*)(ws + 33024);                         // 8*8192 ints
  unsigned short* inpB = (unsigned short*)(ws + 295168);    // 33.5 MB bf16 [8192][2048]
  unsigned short* WeB  = (unsigned short*)(ws + 33849600);  // 67.1 MB bf16 [8][2048][2048]
  const size_t needed = 33849600ull + 67108864ull;

  if (ws_size >= needed) {
    gate_kernel<true><<<dim3(B_TOK / 4), 256, 0, stream>>>(x, y, gW, gb, eid, inpB);
    bucket_cvt<true><<<dim3(NE + CVT_BLOCKS), 256, 0, stream>>>(eid, counts, perm, We, WeB);
    moe_gemm4<<<dim3(2048), 512, 0, stream>>>(be, inpB, WeB, counts, perm, out);
  } else {
    gate_kernel<false><<<dim3(B_TOK / 4), 256, 0, stream>>>(x, y, gW, gb, eid, nullptr);
    bucket_cvt<false><<<dim3(NE), 256, 0, stream>>>(eid, counts, perm, nullptr, nullptr);
    moe_gemm_f32<<<dim3(DIM / BN, B_TOK / BM, NE), 256, 0, stream>>>(
        x, y, We, be, counts, perm, out);
  }
}

// Round 8
// 391.475 us; speedup vs baseline: 1.2321x; 1.0207x over previous
//
#include <hip/hip_runtime.h>
#include <stdint.h>

#define B_TOK 8192
#define DIM   2048
#define NE    8
#define BM 128
#define BN 128
#define BK 64
#define CVT_BLOCKS 8192   // 1024 float4 per block (4 float4 per thread)
#define NT5 64            // 2048 / 32 K-tiles for the 256^2 BK=32 GEMM

typedef __bf16 bf16x8 __attribute__((ext_vector_type(8)));
typedef float  f32x4  __attribute__((ext_vector_type(4)));

__device__ __forceinline__ unsigned short f2b(float f) {
  unsigned u = __builtin_bit_cast(unsigned, f);
  u += 0x7fffu + ((u >> 16) & 1u);   // round-to-nearest-even
  return (unsigned short)(u >> 16);
}
__device__ __forceinline__ uint2 pack4(float4 v) {
  uint2 r;
  r.x = (unsigned)f2b(v.x) | ((unsigned)f2b(v.y) << 16);
  r.y = (unsigned)f2b(v.z) | ((unsigned)f2b(v.w) << 16);
  return r;
}
__device__ __forceinline__ uint2 pack4(f32x4 v) {
  uint2 r;
  r.x = (unsigned)f2b(v.x) | ((unsigned)f2b(v.y) << 16);
  r.y = (unsigned)f2b(v.z) | ((unsigned)f2b(v.w) << 16);
  return r;
}
__device__ __forceinline__ void gload16(const void* g, void* l) {
  __builtin_amdgcn_global_load_lds(
      (const __attribute__((address_space(1))) void*)g,
      (__attribute__((address_space(3))) void*)l, 16, 0, 0);
}

#define SCHEDB __builtin_amdgcn_sched_barrier(0)
#define BARRIER do { SCHEDB; __builtin_amdgcn_s_barrier(); SCHEDB; } while (0)

// ---------------- gating: one wave per token, exact f64, NO atomics --------
template <bool WINP>
__global__ __launch_bounds__(256) void gate_kernel(
    const float* __restrict__ x,
    const float* __restrict__ y,
    const float* __restrict__ gW,
    const float* __restrict__ gb,
    int* __restrict__ eid,
    unsigned short* __restrict__ inpB) {
  const int tid = threadIdx.x;
  const int ln = tid & 63;
  const int token = blockIdx.x * 4 + (tid >> 6);

  double acc[NE];
#pragma unroll
  for (int e = 0; e < NE; ++e) acc[e] = 0.0;

  const float* bases[2] = {x, y};
#pragma unroll
  for (int p = 0; p < 2; ++p) {
    const float* rowp = bases[p] + (size_t)token * 1024;
#pragma unroll
    for (int it = 0; it < 4; ++it) {
      const int d = it * 256 + ln * 4;
      float4 v = *(const float4*)(rowp + d);
      if (WINP)
        *(uint2*)(inpB + (size_t)token * DIM + p * 1024 + d) = pack4(v);
#pragma unroll
      for (int e = 0; e < NE; ++e) {
        float4 g = *(const float4*)(gW + e * DIM + p * 1024 + d);
        acc[e] += (double)v.x * (double)g.x + (double)v.y * (double)g.y +
                  (double)v.z * (double)g.z + (double)v.w * (double)g.w;
      }
    }
  }
#pragma unroll
  for (int e = 0; e < NE; ++e) {
#pragma unroll
    for (int off = 32; off >= 1; off >>= 1) acc[e] += __shfl_xor(acc[e], off, 64);
  }
  if (ln == 0) {
    int best = 0;
    double bv = acc[0] + (double)gb[0];
#pragma unroll
    for (int e = 1; e < NE; ++e) {
      double v = acc[e] + (double)gb[e];
      if (v > bv) { bv = v; best = e; }   // strict > keeps lowest index on ties
    }
    eid[token] = best;
  }
}

// ---------------- bucketize + We conversion, one launch --------------------
// We f32 read is NON-TEMPORAL: the 268 MB stream must not evict inpB/WeB
// from L3 (they are the GEMM's inputs, produced immediately before).
template <bool CVT>
__global__ __launch_bounds__(256) void bucket_cvt(
    const int* __restrict__ eid,
    int* __restrict__ counts,
    int* __restrict__ perm,
    const float* __restrict__ We,
    unsigned short* __restrict__ WeB) {
  if (CVT && blockIdx.x >= NE) {
    const int cb = blockIdx.x - NE;
    const size_t base = (size_t)cb * 1024;   // float4 units
#pragma unroll
    for (int j = 0; j < 4; ++j) {
      size_t i4 = base + (size_t)(j * 256 + threadIdx.x);
      f32x4 v = __builtin_nontemporal_load((const f32x4*)We + i4);
      *(uint2*)(WeB + i4 * 4) = pack4(v);
    }
    return;
  }

  const int e = blockIdx.x;
  const int tid = threadIdx.x, ln = tid & 63, wv = tid >> 6;
  __shared__ int wsum[4];
  __shared__ int basev;
  if (tid == 0) basev = 0;
  __syncthreads();
  for (int t0 = 0; t0 < B_TOK; t0 += 256) {
    int t = t0 + tid;
    bool m = (eid[t] == e);
    unsigned long long mk = __ballot(m);
    int pre = __popcll(mk & ((1ull << ln) - 1ull));
    if (ln == 0) wsum[wv] = __popcll(mk);
    __syncthreads();
    int off = basev;
    for (int w = 0; w < wv; ++w) off += wsum[w];
    if (m) perm[e * B_TOK + off + pre] = t;
    __syncthreads();
    if (tid == 0) basev += wsum[0] + wsum[1] + wsum[2] + wsum[3];
    __syncthreads();
  }
  if (tid == 0) counts[e] = basev;
}

// ---------------- 256x256 8-wave BK=32 grouped GEMM, 2 blocks/CU -----------
// r6 diagnosis: 288 tiles on 256 CUs at 1 block/CU = 2 serial rounds (45%
// idle). Fix: BK 64->32 halves LDS to 64KB(+1K tokLds) -> 2 blocks/CU ->
// one concurrent round; inter-block slip provides the MFMA||LDS||fetch
// overlap (m114) instead of a deep intra-block pipeline.
// Per tile: {12 ds_read_b128 + 4 gload(t+1) | barrier | 32 MFMA (setprio) |
// vmcnt(0) | barrier}. vmcnt flight >= one MFMA phase. WAR: stage(t+1) into
// buf d^1 whose last readers drained before tile t-1's boundary barrier.
// Swizzle (64B rows = 4 chunks): slot = c ^ ((row>>1)&3); per-16-lane
// read quarter -> 2 lanes per 4-bank group (free minimum). Staging source
// chunk g = (ln&3)^((ln>>3)&3) keeps the gload16 LDS dest linear (lane*16).
// Expert->XCD map kept (bid&7): FETCH 174->70 MB proven in r6.
__global__ __launch_bounds__(512, 2) void moe_gemm5(
    const float* __restrict__ be,
    const unsigned short* __restrict__ inpB,   // bf16 [8192][2048]
    const unsigned short* __restrict__ WeB,    // bf16 [8][2048][2048]
    const int* __restrict__ counts,
    const int* __restrict__ perm,
    float* __restrict__ out) {
  __shared__ __align__(16) unsigned short AB[32768];   // A:[2][256][32]@0, B@16384
  __shared__ int tokLds[256];

  const int bid = blockIdx.x;
  const int e = bid & 7;            // XCD id == expert id
  const int j = bid >> 3;
  const int n0 = (j & 7) * 256;
  const int m0 = (j >> 3) * 256;
  const int cnt = counts[e];
  if (m0 >= cnt) return;

  const int tid = threadIdx.x;
  const int ln = tid & 63;
  const int wv = tid >> 6;     // 0..7
  const int wm = wv & 1;       // M-half (128 rows) of C owned by this wave
  const int wn = wv >> 1;      // 0..3 N-quarter (64 cols)

  if (tid < 256) {
    int r = m0 + tid;
    tokLds[tid] = perm[e * B_TOK + (r < cnt ? r : cnt - 1)];
  }
  __syncthreads();

  // staging: issue i covers rows i*128..+128 of the 256-row tile; within a
  // wave: row = i*128 + wv*16 + (ln>>2), slot = ln&3 -> LDS dest linear.
  // global chunk g = slot ^ ((row>>1)&3) = (ln&3) ^ ((ln>>3)&3).
  const int g = (ln & 3) ^ ((ln >> 3) & 3);
  const unsigned short* wbbase = WeB + (size_t)e * DIM * DIM;
  const int row0 = 0 * 128 + wv * 16 + (ln >> 2);
  const int row1 = 1 * 128 + wv * 16 + (ln >> 2);
  const unsigned short* aS0 = inpB + (size_t)tokLds[row0] * DIM + g * 8;
  const unsigned short* aS1 = inpB + (size_t)tokLds[row1] * DIM + g * 8;
  const unsigned short* bS0 = wbbase + (size_t)(n0 + row0) * DIM + g * 8;
  const unsigned short* bS1 = wbbase + (size_t)(n0 + row1) * DIM + g * 8;

  f32x4 acc[8][4];
#pragma unroll
  for (int a = 0; a < 8; ++a)
#pragma unroll
    for (int b = 0; b < 4; ++b) acc[a][b] = (f32x4){0.f, 0.f, 0.f, 0.f};

  // fragment reads: row = base + (ln&15), chunk c = ln>>4 (4 x 8 bf16 = K32),
  // slot = c ^ ((row>>1)&3); bases are multiples of 16 -> ((ln&15)>>1)&3.
  const int slotR = (ln >> 4) ^ (((ln & 15) >> 1) & 3);
  const int aOff = (wm * 128 + (ln & 15)) * 32 + slotR * 8;            // shorts
  const int bOff = 16384 + (wn * 64 + (ln & 15)) * 32 + slotR * 8;     // shorts

  auto SA5 = [&](int tt) {
    if (tt >= NT5) return;
    const int dd = (tt & 1) * 8192;
    const int ko = tt * 32;
    gload16(aS0 + ko, &AB[dd + wv * 512]);
    gload16(aS1 + ko, &AB[dd + 4096 + wv * 512]);
  };
  auto SB5 = [&](int tt) {
    if (tt >= NT5) return;
    const int dd = (tt & 1) * 8192;
    const int ko = tt * 32;
    gload16(bS0 + ko, &AB[16384 + dd + wv * 512]);
    gload16(bS1 + ko, &AB[16384 + dd + 4096 + wv * 512]);
  };

  // prologue: stage tile 0, drain, barrier
  SA5(0); SB5(0);
  asm volatile("s_waitcnt vmcnt(0)" ::: "memory");
  BARRIER;

  for (int t = 0; t < NT5; ++t) {
    const int dd = (t & 1) * 8192;
    bf16x8 av[8], bv[4];
#pragma unroll
    for (int f = 0; f < 8; ++f)
      av[f] = *(const bf16x8*)&AB[dd + aOff + f * 512];
#pragma unroll
    for (int b = 0; b < 4; ++b)
      bv[b] = *(const bf16x8*)&AB[dd + bOff + b * 512];
    SA5(t + 1); SB5(t + 1);
    BARRIER;
    __builtin_amdgcn_s_setprio(1);
#pragma unroll
    for (int f = 0; f < 8; ++f)
#pragma unroll
      for (int b = 0; b < 4; ++b)
        acc[f][b] = __builtin_amdgcn_mfma_f32_16x16x32_bf16(av[f], bv[b], acc[f][b], 0, 0, 0);
    __builtin_amdgcn_s_setprio(0);
    asm volatile("s_waitcnt vmcnt(0)" ::: "memory");   // t+1 landed (flight >= MFMA phase)
    BARRIER;
  }

  // epilogue: += bias, scatter rows by token id, non-temporal f32 store
  float bias[4]; int col[4];
#pragma unroll
  for (int b = 0; b < 4; ++b) {
    col[b] = n0 + wn * 64 + b * 16 + (ln & 15);
    bias[b] = be[e * DIM + col[b]];
  }
#pragma unroll
  for (int a = 0; a < 8; ++a) {
    int rbase = wm * 128 + a * 16 + ((ln >> 4) << 2);
#pragma unroll
    for (int r = 0; r < 4; ++r) {
      int rl = rbase + r;
      if (m0 + rl < cnt) {
        size_t t = (size_t)tokLds[rl];
#pragma unroll
        for (int b = 0; b < 4; ++b)
          __builtin_nontemporal_store(acc[a][b][r] + bias[b],
                                      &out[t * DIM + col[b]]);
      }
    }
  }
}

// ---------------- fallback GEMM (f32 sources, no workspace) ----------------
__global__ __launch_bounds__(256) void moe_gemm_f32(
    const float* __restrict__ x,
    const float* __restrict__ y,
    const float* __restrict__ We,
    const float* __restrict__ be,
    const int* __restrict__ counts,
    const int* __restrict__ perm,
    float* __restrict__ out) {
  __shared__ unsigned short As[BM * BK];
  __shared__ unsigned short Bs[BN * BK];
  __shared__ int tokLds[BM];

  const int e = blockIdx.z;
  const int cnt = counts[e];
  const int m0 = blockIdx.y * BM;
  if (m0 >= cnt) return;
  const int n0 = blockIdx.x * BN;

  const int tid = threadIdx.x;
  const int ln = tid & 63;
  const int wv = tid >> 6;
  const int wm = wv & 1, wn = wv >> 1;

  if (tid < BM) {
    int r = m0 + tid;
    tokLds[tid] = perm[e * B_TOK + (r < cnt ? r : cnt - 1)];
  }
  __syncthreads();

  const float* wfbase = We + (size_t)e * DIM * DIM;

  f32x4 acc[4][4];
#pragma unroll
  for (int i = 0; i < 4; ++i)
#pragma unroll
    for (int j = 0; j < 4; ++j) acc[i][j] = (f32x4){0.f, 0.f, 0.f, 0.f};

  for (int k0 = 0; k0 < DIM; k0 += BK) {
    __syncthreads();
    const float* ab = (k0 < 1024) ? x : y;
    const int kk = k0 & 1023;
#pragma unroll
    for (int i = 0; i < 8; ++i) {
      int li = i * 256 + tid;
      int row = li >> 4, k4 = li & 15;
      int chunk = k4 >> 1, half = k4 & 1;
      int slot = (chunk ^ (row & 7)) * 2 + half;
      int tok = tokLds[row];
      float4 va = *(const float4*)(ab + (size_t)tok * 1024 + kk + k4 * 4);
      *(uint2*)&As[row * BK + slot * 4] = pack4(va);
      float4 vb = *(const float4*)(wfbase + (size_t)(n0 + row) * DIM + k0 + k4 * 4);
      *(uint2*)&Bs[row * BK + slot * 4] = pack4(vb);
    }
    __syncthreads();

#pragma unroll
    for (int ks = 0; ks < 2; ++ks) {
      bf16x8 av[4], bv[4];
#pragma unroll
      for (int i = 0; i < 4; ++i) {
        int rA = wm * 64 + i * 16 + (ln & 15);
        int c = ks * 4 + (ln >> 4);
        av[i] = *(const bf16x8*)&As[rA * BK + (c ^ (rA & 7)) * 8];
      }
#pragma unroll
      for (int j = 0; j < 4; ++j) {
        int rB = wn * 64 + j * 16 + (ln & 15);
        int c = ks * 4 + (ln >> 4);
        bv[j] = *(const bf16x8*)&Bs[rB * BK + (c ^ (rB & 7)) * 8];
      }
#pragma unroll
      for (int i = 0; i < 4; ++i)
#pragma unroll
        for (int j = 0; j < 4; ++j)
          acc[i][j] = __builtin_amdgcn_mfma_f32_16x16x32_bf16(av[i], bv[j], acc[i][j], 0, 0, 0);
    }
  }

  float bias[4]; int col[4];
#pragma unroll
  for (int j = 0; j < 4; ++j) {
    col[j] = n0 + wn * 64 + j * 16 + (ln & 15);
    bias[j] = be[e * DIM + col[j]];
  }
#pragma unroll
  for (int i = 0; i < 4; ++i) {
    int rbase = wm * 64 + i * 16 + ((ln >> 4) << 2);
#pragma unroll
    for (int r = 0; r < 4; ++r) {
      int rl = rbase + r;
      if (m0 + rl < cnt) {
        size_t t = (size_t)tokLds[rl];
#pragma unroll
        for (int j = 0; j < 4; ++j)
          out[t * DIM + col[j]] = acc[i][j][r] + bias[j];
      }
    }
  }
}

extern "C" void kernel_launch(void* const* d_in, const int* in_sizes, int n_in,
                              void* d_out, int out_size, void* d_ws, size_t ws_size,
                              hipStream_t stream) {
  const float* x  = (const float*)d_in[0];
  const float* y  = (const float*)d_in[1];
  const float* We = (const float*)d_in[2];
  const float* be = (const float*)d_in[3];
  const float* gW = (const float*)d_in[4];
  const float* gb = (const float*)d_in[5];
  float* out = (float*)d_out;

  char* ws = (char*)d_ws;
  int* counts = (int*)ws;                                   // @0, 8 ints (256B pad)
  int* eid    = (int*)(ws + 256);                           // 8192 ints
  int* perm   = (int*)(ws + 33024);                         // 8*8192 ints
  unsigned short* inpB = (unsigned short*)(ws + 295168);    // 33.5 MB bf16 [8192][2048]
  unsigned short* WeB  = (unsigned short*)(ws + 33849600);  // 67.1 MB bf16 [8][2048][2048]
  const size_t needed = 33849600ull + 67108864ull;

  if (ws_size >= needed) {
    gate_kernel<true><<<dim3(B_TOK / 4), 256, 0, stream>>>(x, y, gW, gb, eid, inpB);
    bucket_cvt<true><<<dim3(NE + CVT_BLOCKS), 256, 0, stream>>>(eid, counts, perm, We, WeB);
    moe_gemm5<<<dim3(2048), 512, 0, stream>>>(be, inpB, WeB, counts, perm, out);
  } else {
    gate_kernel<false><<<dim3(B_TOK / 4), 256, 0, stream>>>(x, y, gW, gb, eid, nullptr);
    bucket_cvt<false><<<dim3(NE), 256, 0, stream>>>(eid, counts, perm, nullptr, nullptr);
    moe_gemm_f32<<<dim3(DIM / BN, B_TOK / BM, NE), 256, 0, stream>>>(
        x, y, We, be, counts, perm, out);
  }
}